// Round 5
// baseline (40327.551 us; speedup 1.0000x reference)
//
#include <hip/hip_runtime.h>

typedef unsigned short u16;
typedef __attribute__((ext_vector_type(8))) short short8;
typedef __attribute__((ext_vector_type(4))) float f32x4;

#define NB 256      // batch
#define TE 512      // encoder T
#define DK 256      // key dim
#define DV 256      // value dim
#define HH 512      // hidden
#define NV 35       // vocab
#define STEPS 300
#define TLEN 301
#define K1 1280     // LSTM1 inner dim: emb(512) + ctx(256) + h1(512)
#define K2 768      // LSTM2 inner dim: h1(512) + h2(256)

__device__ __forceinline__ float bf2f(u16 u){ return __uint_as_float(((unsigned)u)<<16); }
__device__ __forceinline__ u16 f2bf(float f){
  unsigned u = __float_as_uint(f);
  u += 0x7fffu + ((u>>16)&1u);   // RNE
  return (u16)(u>>16);
}
__device__ __forceinline__ void splitbf(float f, short& hi, short& lo){
  u16 h = f2bf(f);
  float r = f - bf2f(h);
  hi = (short)h; lo = (short)f2bf(r);
}
__device__ __forceinline__ float sigm(float x){ return 1.f/(1.f+expf(-x)); }

// ---------------- conversion kernel (once per launch) ----------------
// dst rows = [s1 row (k1 cols) | s2 row (k2 cols)], split to hi/lo bf16
__global__ void conv_cat_split(u16* __restrict__ dhi, u16* __restrict__ dlo,
                               const float* __restrict__ s1, const float* __restrict__ s2,
                               int k1, int k2, int total8){
  int i = blockIdx.x*blockDim.x + threadIdx.x;
  if (i >= total8) return;
  int ktot = k1 + k2;
  long e = (long)i*8;
  int r = (int)(e / ktot); int k = (int)(e - (long)r*ktot);
  const float* s = (k < k1) ? (s1 + (size_t)r*k1 + k) : (s2 + (size_t)r*k2 + (k-k1));
  short8 oh, ol;
  #pragma unroll
  for (int q=0;q<8;++q){ short h,l; splitbf(s[q],h,l); oh[q]=h; ol[q]=l; }
  *(short8*)(dhi + e) = oh;
  *(short8*)(dlo + e) = ol;
}

// stage helper: split 8 f32 into hi/lo bf16 vectors
__device__ __forceinline__ void split8(const float* x, short8& vh, short8& vl){
  #pragma unroll
  for (int q=0;q<8;++q){ short h,l; splitbf(x[q],h,l); vh[q]=h; vl[q]=l; }
}

// ---------------- LSTM1: gates GEMM [256 x 1280]·[1280 x 2048] + cell update ----------------
// A = [emb[text[:,t]] (512) | ctx (256) | h1_old (512)]  (f32 states, hi/lo split on stage)
// W split hi/lo; acc = Ah·Wh + Al·Wh + Ah·Wl  (~17-bit operand precision)
__global__ __launch_bounds__(128) void lstm1_k(
  const int* __restrict__ text, int t, int par,
  const float* __restrict__ emb,
  const float* __restrict__ ctx,
  float* __restrict__ h1b,
  float* __restrict__ c1,
  const u16* __restrict__ Whi, const u16* __restrict__ Wlo,
  const float* __restrict__ b_ih, const float* __restrict__ b_hh)
{
  __shared__ __align__(16) u16 Ah[2][4][16][8], Al[2][4][16][8];
  __shared__ __align__(16) u16 Bh[4][4][16][8], Bl[4][4][16][8];
  const float* h1_old = h1b + (size_t)par*NB*HH;
  float* h1_new = h1b + (size_t)(par^1)*NB*HH;
  int b = blockIdx.x;
  // XCD swizzle: XCD x hosts jh tiles 4x..4x+3 for all n-tiles (B-panel L2 reuse)
  int jh0 = ((b&7)*4 + ((b>>3)&3))*16;
  int n0 = (b>>5)*32;
  int tid = threadIdx.x;
  int w = tid>>6, lane = tid&63;
  int an = tid>>2, ak = (tid&3)*8;
  int arow = n0 + an;
  const float* aemb = emb + (size_t)text[arow*TLEN + t]*HH;
  const float* actx = ctx + (size_t)arow*DV;
  const float* ah1  = h1_old + (size_t)arow*HH;
  f32x4 zero = {0.f,0.f,0.f,0.f};
  f32x4 acc[4];
  #pragma unroll
  for (int g=0;g<4;++g) acc[g]=zero;
  for (int k0=0; k0<K1; k0+=32){
    int k = k0 + ak;
    const float* src = (k<512)? (aemb+k) : (k<768)? (actx + (k-512)) : (ah1 + (k-768));
    float xs[8];
    *(float4*)&xs[0] = *(const float4*)src;
    *(float4*)&xs[4] = *(const float4*)(src+4);
    short8 avh, avl;
    split8(xs, avh, avl);
    *(short8*)&Ah[an>>4][ak>>3][an&15][0] = avh;
    *(short8*)&Al[an>>4][ak>>3][an&15][0] = avl;
    #pragma unroll
    for (int uu=0; uu<2; ++uu){
      int u = tid*2+uu;
      int jl = u>>2, ko=(u&3)*8;
      int j = (jl>>4)*512 + jh0 + (jl&15);
      *(short8*)&Bh[jl>>4][ko>>3][jl&15][0] = *(const short8*)(Whi + (size_t)j*K1 + (k0+ko));
      *(short8*)&Bl[jl>>4][ko>>3][jl&15][0] = *(const short8*)(Wlo + (size_t)j*K1 + (k0+ko));
    }
    __syncthreads();
    short8 afh = *(const short8*)&Ah[w][lane>>4][lane&15][0];
    short8 afl = *(const short8*)&Al[w][lane>>4][lane&15][0];
    #pragma unroll
    for (int g=0; g<4; ++g){
      short8 bh = *(const short8*)&Bh[g][lane>>4][lane&15][0];
      short8 bl = *(const short8*)&Bl[g][lane>>4][lane&15][0];
      acc[g] = __builtin_amdgcn_mfma_f32_16x16x32_bf16(afh, bh, acc[g], 0,0,0);
      acc[g] = __builtin_amdgcn_mfma_f32_16x16x32_bf16(afl, bh, acc[g], 0,0,0);
      acc[g] = __builtin_amdgcn_mfma_f32_16x16x32_bf16(afh, bl, acc[g], 0,0,0);
    }
    __syncthreads();
  }
  int col = lane&15, jh = jh0+col;
  float bi  = b_ih[jh]      + b_hh[jh];
  float bff = b_ih[HH+jh]   + b_hh[HH+jh];
  float bg  = b_ih[2*HH+jh] + b_hh[2*HH+jh];
  float bo  = b_ih[3*HH+jh] + b_hh[3*HH+jh];
  #pragma unroll
  for (int r=0;r<4;++r){
    int n = n0 + w*16 + (lane>>4)*4 + r;
    size_t idx = (size_t)n*HH + jh;
    float iv = sigm(acc[0][r]+bi);
    float fv = sigm(acc[1][r]+bff);
    float gv = tanhf(acc[2][r]+bg);
    float ov = sigm(acc[3][r]+bo);
    float cn = fv*c1[idx] + iv*gv;
    c1[idx] = cn;
    h1_new[idx] = ov*tanhf(cn);
  }
}

// ---------------- LSTM2: [256 x 768]·[768 x 1024] + cell update ----------------
__global__ __launch_bounds__(128) void lstm2_k(
  int par,
  const float* __restrict__ h1b,
  float* __restrict__ h2b,
  float* __restrict__ c2,
  const u16* __restrict__ Whi, const u16* __restrict__ Wlo,
  const float* __restrict__ b_ih, const float* __restrict__ b_hh)
{
  __shared__ __align__(16) u16 Ah[2][4][16][8], Al[2][4][16][8];
  __shared__ __align__(16) u16 Bh[4][4][16][8], Bl[4][4][16][8];
  const float* h1_cur = h1b + (size_t)(par^1)*NB*HH;
  const float* h2_old = h2b + (size_t)par*NB*DK;
  float* h2_new = h2b + (size_t)(par^1)*NB*DK;
  int b = blockIdx.x;
  int jh0 = ((b&7)*2 + ((b>>3)&1))*16;
  int n0 = (b>>4)*32;
  int tid = threadIdx.x;
  int w = tid>>6, lane = tid&63;
  int an = tid>>2, ak = (tid&3)*8;
  int arow = n0 + an;
  const float* ah1 = h1_cur + (size_t)arow*HH;
  const float* ah2 = h2_old + (size_t)arow*DK;
  f32x4 zero = {0.f,0.f,0.f,0.f};
  f32x4 acc[4];
  #pragma unroll
  for (int g=0;g<4;++g) acc[g]=zero;
  for (int k0=0; k0<K2; k0+=32){
    int k = k0 + ak;
    const float* src = (k<512)? (ah1+k) : (ah2 + (k-512));
    float xs[8];
    *(float4*)&xs[0] = *(const float4*)src;
    *(float4*)&xs[4] = *(const float4*)(src+4);
    short8 avh, avl;
    split8(xs, avh, avl);
    *(short8*)&Ah[an>>4][ak>>3][an&15][0] = avh;
    *(short8*)&Al[an>>4][ak>>3][an&15][0] = avl;
    #pragma unroll
    for (int uu=0; uu<2; ++uu){
      int u = tid*2+uu;
      int jl = u>>2, ko=(u&3)*8;
      int j = (jl>>4)*256 + jh0 + (jl&15);
      *(short8*)&Bh[jl>>4][ko>>3][jl&15][0] = *(const short8*)(Whi + (size_t)j*K2 + (k0+ko));
      *(short8*)&Bl[jl>>4][ko>>3][jl&15][0] = *(const short8*)(Wlo + (size_t)j*K2 + (k0+ko));
    }
    __syncthreads();
    short8 afh = *(const short8*)&Ah[w][lane>>4][lane&15][0];
    short8 afl = *(const short8*)&Al[w][lane>>4][lane&15][0];
    #pragma unroll
    for (int g=0; g<4; ++g){
      short8 bh = *(const short8*)&Bh[g][lane>>4][lane&15][0];
      short8 bl = *(const short8*)&Bl[g][lane>>4][lane&15][0];
      acc[g] = __builtin_amdgcn_mfma_f32_16x16x32_bf16(afh, bh, acc[g], 0,0,0);
      acc[g] = __builtin_amdgcn_mfma_f32_16x16x32_bf16(afl, bh, acc[g], 0,0,0);
      acc[g] = __builtin_amdgcn_mfma_f32_16x16x32_bf16(afh, bl, acc[g], 0,0,0);
    }
    __syncthreads();
  }
  int col = lane&15, jh = jh0+col;
  float bi  = b_ih[jh]      + b_hh[jh];
  float bff = b_ih[DK+jh]   + b_hh[DK+jh];
  float bg  = b_ih[2*DK+jh] + b_hh[2*DK+jh];
  float bo  = b_ih[3*DK+jh] + b_hh[3*DK+jh];
  #pragma unroll
  for (int r=0;r<4;++r){
    int n = n0 + w*16 + (lane>>4)*4 + r;
    size_t idx = (size_t)n*DK + jh;
    float iv = sigm(acc[0][r]+bi);
    float fv = sigm(acc[1][r]+bff);
    float gv = tanhf(acc[2][r]+bg);
    float ov = sigm(acc[3][r]+bo);
    float cn = fv*c2[idx] + iv*gv;
    c2[idx] = cn;
    h2_new[idx] = ov*tanhf(cn);
  }
}

// ---------------- attention + softmax + ctx + output projection; one block per n ----------------
// keys AND values f32 (value rounding injects directly into ctx -> dominant error path)
__global__ __launch_bounds__(256) void attn_k(
  const float* __restrict__ keys, const float* __restrict__ vals,
  const int* __restrict__ lens,
  const float* __restrict__ h2b, int par,
  float* __restrict__ ctx,
  const float* __restrict__ Wout, const float* __restrict__ b_out,
  float* __restrict__ out, int t)
{
  __shared__ float h2s[DK];
  __shared__ float e_s[TE];
  __shared__ float a_s[TE];
  __shared__ float ctx_s[DV];
  __shared__ float red_s[8];
  __shared__ __align__(16) float ks[32][260];   // +4 pad
  int n = blockIdx.x, tid = threadIdx.x;
  const float* h2cur = h2b + (size_t)(par^1)*NB*DK;
  int L = lens[n] >> 3;           // lens // 8; only t < L are unmasked
  h2s[tid] = h2cur[n*DK + tid];
  __syncthreads();
  for (int t0=0; t0<L; t0+=32){
    int nr = min(32, L-t0);
    for (int u=tid; u<nr*64; u+=256){
      int r = u>>6, c = u&63;
      *(float4*)&ks[r][c*4] = *(const float4*)(keys + (size_t)(n*TE + t0 + r)*DK + c*4);
    }
    __syncthreads();
    int r = tid>>3, kl = tid&7;
    if (r < nr){
      float s = 0.f;
      #pragma unroll
      for (int d=0; d<32; ++d){
        int k = kl + d*8;
        s += ks[r][k] * h2s[k];
      }
      s += __shfl_xor(s,1); s += __shfl_xor(s,2); s += __shfl_xor(s,4);
      if (kl==0) e_s[t0+r] = s;
    }
    __syncthreads();
  }
  // softmax over t < L
  float v1 = (tid     < L)? e_s[tid]     : -1e30f;
  float v2 = (tid+256 < L)? e_s[tid+256] : -1e30f;
  float m = fmaxf(v1,v2);
  #pragma unroll
  for (int o=1;o<64;o<<=1) m = fmaxf(m, __shfl_xor(m,o));
  if ((tid&63)==0) red_s[tid>>6] = m;
  __syncthreads();
  m = fmaxf(fmaxf(red_s[0],red_s[1]), fmaxf(red_s[2],red_s[3]));
  float p1 = (tid<L)?     expf(v1-m) : 0.f;
  float p2 = (tid+256<L)? expf(v2-m) : 0.f;
  float sm = p1+p2;
  #pragma unroll
  for (int o=1;o<64;o<<=1) sm += __shfl_xor(sm,o);
  if ((tid&63)==0) red_s[4+(tid>>6)] = sm;
  __syncthreads();
  sm = red_s[4]+red_s[5]+red_s[6]+red_s[7];
  float inv = 1.f/sm;
  a_s[tid]     = p1*inv;
  a_s[tid+256] = p2*inv;
  __syncthreads();
  // ctx[v] = sum_t a[t] * vals[n][t][v]   (f32 values, coalesced row reads)
  float cv = 0.f;
  {
    const float* vp = vals + (size_t)n*TE*DV + tid;
    int tt=0;
    for (; tt+4<=L; tt+=4){
      float a0=a_s[tt],a1=a_s[tt+1],a2=a_s[tt+2],a3=a_s[tt+3];
      float x0=vp[(size_t)(tt+0)*DV];
      float x1=vp[(size_t)(tt+1)*DV];
      float x2=vp[(size_t)(tt+2)*DV];
      float x3=vp[(size_t)(tt+3)*DV];
      cv += a0*x0+a1*x1+a2*x2+a3*x3;
    }
    for (; tt<L; ++tt) cv += a_s[tt]*vp[(size_t)tt*DV];
  }
  ctx_s[tid] = cv;
  ctx[(size_t)n*DV + tid] = cv;
  __syncthreads();
  // pred[v] = [h2 | ctx] . W_out[v] + b_out[v]   (W_out in f32)
  #pragma unroll
  for (int vb=0; vb<2; ++vb){
    int vv = vb*32 + (tid>>3);
    if (vv < NV){
      int kp = (tid&7)*64;
      float s = 0.f;
      #pragma unroll
      for (int d=0; d<64; d+=4){
        float4 wv = *(const float4*)(Wout + (size_t)vv*512 + kp + d);
        int k = kp+d;
        float x0 = (k<DK)?   h2s[k]   : ctx_s[k-DK];
        float x1 = (k+1<DK)? h2s[k+1] : ctx_s[k+1-DK];
        float x2 = (k+2<DK)? h2s[k+2] : ctx_s[k+2-DK];
        float x3 = (k+3<DK)? h2s[k+3] : ctx_s[k+3-DK];
        s += wv.x*x0 + wv.y*x1 + wv.z*x2 + wv.w*x3;
      }
      s += __shfl_xor(s,1); s += __shfl_xor(s,2); s += __shfl_xor(s,4);
      if ((tid&7)==0) out[((size_t)n*STEPS + t)*NV + vv] = s + b_out[vv];
    }
  }
}

// ---------------- host ----------------
extern "C" void kernel_launch(void* const* d_in, const int* in_sizes, int n_in,
                              void* d_out, int out_size, void* d_ws, size_t ws_size,
                              hipStream_t stream)
{
  const float* enc_key = (const float*)d_in[0];
  const float* enc_val = (const float*)d_in[1];
  const int*   text    = (const int*)d_in[2];
  const int*   lens    = (const int*)d_in[3];
  const float* emb     = (const float*)d_in[5];
  const float* W_ih1   = (const float*)d_in[6];
  const float* W_hh1   = (const float*)d_in[7];
  const float* b_ih1   = (const float*)d_in[8];
  const float* b_hh1   = (const float*)d_in[9];
  const float* W_ih2   = (const float*)d_in[10];
  const float* W_hh2   = (const float*)d_in[11];
  const float* b_ih2   = (const float*)d_in[12];
  const float* b_hh2   = (const float*)d_in[13];
  const float* W_out   = (const float*)d_in[14];
  const float* b_out   = (const float*)d_in[15];
  float* out = (float*)d_out;

  char* ws = (char*)d_ws;
  size_t off = 0;
  auto alloc = [&](size_t bytes)->char*{
    char* p = ws + off; off = (off + bytes + 255) & ~(size_t)255; return p;
  };

  u16* Wc1h = (u16*)alloc((size_t)2048*K1*2);     // 5.24 MB
  u16* Wc1l = (u16*)alloc((size_t)2048*K1*2);
  u16* Wc2h = (u16*)alloc((size_t)1024*K2*2);     // 1.57 MB
  u16* Wc2l = (u16*)alloc((size_t)1024*K2*2);
  float* h1b = (float*)alloc((size_t)2*NB*HH*4);
  float* h2b = (float*)alloc((size_t)2*NB*DK*4);
  float* ctx = (float*)alloc((size_t)NB*DV*4);
  float* c1  = (float*)alloc((size_t)NB*HH*4);
  float* c2  = (float*)alloc((size_t)NB*DK*4);

  // zero recurrent state (contiguous block h1b..c2)
  size_t zbytes = (char*)c2 + (size_t)NB*DK*4 - (char*)h1b;
  (void)hipMemsetAsync(h1b, 0, zbytes, stream);

  // one-time weight conversions (hi/lo split, concatenated [W_ih | W_hh])
  {
    int t8 = 2048*K1/8;
    conv_cat_split<<<(t8+255)/256, 256, 0, stream>>>(Wc1h, Wc1l, W_ih1, W_hh1, 768, 512, t8);
  }
  {
    int t8 = 1024*K2/8;
    conv_cat_split<<<(t8+255)/256, 256, 0, stream>>>(Wc2h, Wc2l, W_ih2, W_hh2, 512, 256, t8);
  }

  for (int t=0; t<STEPS; ++t){
    int par = t&1;
    lstm1_k<<<256, 128, 0, stream>>>(text, t, par, emb, ctx, h1b, c1, Wc1h, Wc1l, b_ih1, b_hh1);
    lstm2_k<<<128, 128, 0, stream>>>(par, h1b, h2b, c2, Wc2h, Wc2l, b_ih2, b_hh2);
    attn_k<<<256, 256, 0, stream>>>(enc_key, enc_val, lens, h2b, par, ctx, W_out, b_out, out, t);
  }
}

// Round 6
// 25588.330 us; speedup vs baseline: 1.5760x; 1.5760x over previous
//
#include <hip/hip_runtime.h>

typedef unsigned short u16;
typedef __attribute__((ext_vector_type(8))) short short8;
typedef __attribute__((ext_vector_type(4))) float f32x4;

#define NB 256      // batch
#define TE 512      // encoder T
#define DK 256      // key dim
#define DV 256      // value dim
#define HH 512      // hidden
#define NV 35       // vocab
#define STEPS 300
#define TLEN 301
#define K1 1280     // LSTM1 inner dim: emb(512) + ctx(256) + h1(512)
#define K2 768      // LSTM2 inner dim: h1(512) + h2(256)

__device__ __forceinline__ float bf2f(u16 u){ return __uint_as_float(((unsigned)u)<<16); }
__device__ __forceinline__ u16 f2bf(float f){
  unsigned u = __float_as_uint(f);
  u += 0x7fffu + ((u>>16)&1u);   // RNE
  return (u16)(u>>16);
}
__device__ __forceinline__ void splitbf(float f, short& hi, short& lo){
  u16 h = f2bf(f);
  float r = f - bf2f(h);
  hi = (short)h; lo = (short)f2bf(r);
}
__device__ __forceinline__ float sigm(float x){ return 1.f/(1.f+expf(-x)); }

// ---------------- conversion kernel (once per launch) ----------------
__global__ void conv_cat_split(u16* __restrict__ dhi, u16* __restrict__ dlo,
                               const float* __restrict__ s1, const float* __restrict__ s2,
                               int k1, int k2, int total8){
  int i = blockIdx.x*blockDim.x + threadIdx.x;
  if (i >= total8) return;
  int ktot = k1 + k2;
  long e = (long)i*8;
  int r = (int)(e / ktot); int k = (int)(e - (long)r*ktot);
  const float* s = (k < k1) ? (s1 + (size_t)r*k1 + k) : (s2 + (size_t)r*k2 + (k-k1));
  short8 oh, ol;
  #pragma unroll
  for (int q=0;q<8;++q){ short h,l; splitbf(s[q],h,l); oh[q]=h; ol[q]=l; }
  *(short8*)(dhi + e) = oh;
  *(short8*)(dlo + e) = ol;
}

__device__ __forceinline__ void split8(const float* x, short8& vh, short8& vl){
  #pragma unroll
  for (int q=0;q<8;++q){ short h,l; splitbf(x[q],h,l); vh[q]=h; vl[q]=l; }
}

// ---------------- LSTM1: gates GEMM [256 x 1280]·[1280 x 2048] + cell update ----------------
// Double-buffered LDS + register prefetch, 1 barrier/iter.
__global__ __launch_bounds__(128) void lstm1_k(
  const int* __restrict__ text, int t, int par,
  const float* __restrict__ emb,
  const float* __restrict__ ctx,
  float* __restrict__ h1b,
  float* __restrict__ c1,
  const u16* __restrict__ Whi, const u16* __restrict__ Wlo,
  const float* __restrict__ b_ih, const float* __restrict__ b_hh)
{
  __shared__ __align__(16) u16 Ah[2][2][4][16][8], Al[2][2][4][16][8];   // [buf][nhalf][kc][row][8]
  __shared__ __align__(16) u16 Bh[2][4][4][16][8], Bl[2][4][4][16][8];   // [buf][gate][kc][j][8]
  const float* h1_old = h1b + (size_t)par*NB*HH;
  float* h1_new = h1b + (size_t)(par^1)*NB*HH;
  int b = blockIdx.x;
  int jh0 = ((b&7)*4 + ((b>>3)&3))*16;   // XCD swizzle for B-panel L2 reuse
  int n0 = (b>>5)*32;
  int tid = threadIdx.x;
  int w = tid>>6, lane = tid&63;
  // A staging coords
  int an = tid>>2, ak = (tid&3)*8;
  int arow = n0 + an;
  const float* aemb = emb + (size_t)text[arow*TLEN + t]*HH;
  const float* actx = ctx + (size_t)arow*DV;
  const float* ah1  = h1_old + (size_t)arow*HH;
  // B staging coords: thread covers row jl at k-offsets (tid&1)*16 +{0,8}
  int jl   = tid>>1;
  int gate = tid>>5;
  int jcol = (tid>>1)&15;
  int kc   = (tid&1)*2;
  int jrow = (jl>>4)*512 + jh0 + (jl&15);
  const u16* pBh = Whi + (size_t)jrow*K1 + (tid&1)*16;
  const u16* pBl = Wlo + (size_t)jrow*K1 + (tid&1)*16;

  f32x4 zero = {0.f,0.f,0.f,0.f};
  f32x4 acc[4];
  #pragma unroll
  for (int g=0;g<4;++g) acc[g]=zero;

  // prefetch iter 0
  float4 a0, a1; short8 rbh0, rbh1, rbl0, rbl1;
  {
    int k = ak;
    const float* src = (k<512)? (aemb+k) : (k<768)? (actx+(k-512)) : (ah1+(k-768));
    a0 = *(const float4*)src; a1 = *(const float4*)(src+4);
    rbh0 = *(const short8*)(pBh);     rbh1 = *(const short8*)(pBh + 8);
    rbl0 = *(const short8*)(pBl);     rbl1 = *(const short8*)(pBl + 8);
  }
  int cur = 0;
  for (int k0=0; k0<K1; k0+=32){
    // split + store current
    float xs[8];
    *(float4*)&xs[0] = a0; *(float4*)&xs[4] = a1;
    short8 avh, avl;
    split8(xs, avh, avl);
    *(short8*)&Ah[cur][an>>4][ak>>3][an&15][0] = avh;
    *(short8*)&Al[cur][an>>4][ak>>3][an&15][0] = avl;
    *(short8*)&Bh[cur][gate][kc  ][jcol][0] = rbh0;
    *(short8*)&Bh[cur][gate][kc+1][jcol][0] = rbh1;
    *(short8*)&Bl[cur][gate][kc  ][jcol][0] = rbl0;
    *(short8*)&Bl[cur][gate][kc+1][jcol][0] = rbl1;
    // prefetch next (in flight across barrier + MFMA)
    if (k0+32 < K1){
      int k = k0+32+ak;
      const float* src = (k<512)? (aemb+k) : (k<768)? (actx+(k-512)) : (ah1+(k-768));
      a0 = *(const float4*)src; a1 = *(const float4*)(src+4);
      rbh0 = *(const short8*)(pBh + k0+32);  rbh1 = *(const short8*)(pBh + k0+40);
      rbl0 = *(const short8*)(pBl + k0+32);  rbl1 = *(const short8*)(pBl + k0+40);
    }
    __syncthreads();
    short8 afh = *(const short8*)&Ah[cur][w][lane>>4][lane&15][0];
    short8 afl = *(const short8*)&Al[cur][w][lane>>4][lane&15][0];
    #pragma unroll
    for (int g=0; g<4; ++g){
      short8 bh = *(const short8*)&Bh[cur][g][lane>>4][lane&15][0];
      short8 bl = *(const short8*)&Bl[cur][g][lane>>4][lane&15][0];
      acc[g] = __builtin_amdgcn_mfma_f32_16x16x32_bf16(afh, bh, acc[g], 0,0,0);
      acc[g] = __builtin_amdgcn_mfma_f32_16x16x32_bf16(afl, bh, acc[g], 0,0,0);
      acc[g] = __builtin_amdgcn_mfma_f32_16x16x32_bf16(afh, bl, acc[g], 0,0,0);
    }
    cur ^= 1;
  }
  int col = lane&15, jh = jh0+col;
  float bi  = b_ih[jh]      + b_hh[jh];
  float bff = b_ih[HH+jh]   + b_hh[HH+jh];
  float bg  = b_ih[2*HH+jh] + b_hh[2*HH+jh];
  float bo  = b_ih[3*HH+jh] + b_hh[3*HH+jh];
  #pragma unroll
  for (int r=0;r<4;++r){
    int n = n0 + w*16 + (lane>>4)*4 + r;
    size_t idx = (size_t)n*HH + jh;
    float iv = sigm(acc[0][r]+bi);
    float fv = sigm(acc[1][r]+bff);
    float gv = tanhf(acc[2][r]+bg);
    float ov = sigm(acc[3][r]+bo);
    float cn = fv*c1[idx] + iv*gv;
    c1[idx] = cn;
    h1_new[idx] = ov*tanhf(cn);
  }
}

// ---------------- LSTM2: [256 x 768]·[768 x 1024] + cell update ----------------
__global__ __launch_bounds__(128) void lstm2_k(
  int par,
  const float* __restrict__ h1b,
  float* __restrict__ h2b,
  float* __restrict__ c2,
  const u16* __restrict__ Whi, const u16* __restrict__ Wlo,
  const float* __restrict__ b_ih, const float* __restrict__ b_hh)
{
  __shared__ __align__(16) u16 Ah[2][2][4][16][8], Al[2][2][4][16][8];
  __shared__ __align__(16) u16 Bh[2][4][4][16][8], Bl[2][4][4][16][8];
  const float* h1_cur = h1b + (size_t)(par^1)*NB*HH;
  const float* h2_old = h2b + (size_t)par*NB*DK;
  float* h2_new = h2b + (size_t)(par^1)*NB*DK;
  int b = blockIdx.x;
  int jh0 = ((b&7)*2 + ((b>>3)&1))*16;
  int n0 = (b>>4)*32;
  int tid = threadIdx.x;
  int w = tid>>6, lane = tid&63;
  int an = tid>>2, ak = (tid&3)*8;
  int arow = n0 + an;
  const float* ah1 = h1_cur + (size_t)arow*HH;
  const float* ah2 = h2_old + (size_t)arow*DK;
  int jl   = tid>>1;
  int gate = tid>>5;
  int jcol = (tid>>1)&15;
  int kc   = (tid&1)*2;
  int jrow = (jl>>4)*256 + jh0 + (jl&15);
  const u16* pBh = Whi + (size_t)jrow*K2 + (tid&1)*16;
  const u16* pBl = Wlo + (size_t)jrow*K2 + (tid&1)*16;

  f32x4 zero = {0.f,0.f,0.f,0.f};
  f32x4 acc[4];
  #pragma unroll
  for (int g=0;g<4;++g) acc[g]=zero;

  float4 a0, a1; short8 rbh0, rbh1, rbl0, rbl1;
  {
    int k = ak;
    const float* src = (k<512)? (ah1+k) : (ah2+(k-512));
    a0 = *(const float4*)src; a1 = *(const float4*)(src+4);
    rbh0 = *(const short8*)(pBh);     rbh1 = *(const short8*)(pBh + 8);
    rbl0 = *(const short8*)(pBl);     rbl1 = *(const short8*)(pBl + 8);
  }
  int cur = 0;
  for (int k0=0; k0<K2; k0+=32){
    float xs[8];
    *(float4*)&xs[0] = a0; *(float4*)&xs[4] = a1;
    short8 avh, avl;
    split8(xs, avh, avl);
    *(short8*)&Ah[cur][an>>4][ak>>3][an&15][0] = avh;
    *(short8*)&Al[cur][an>>4][ak>>3][an&15][0] = avl;
    *(short8*)&Bh[cur][gate][kc  ][jcol][0] = rbh0;
    *(short8*)&Bh[cur][gate][kc+1][jcol][0] = rbh1;
    *(short8*)&Bl[cur][gate][kc  ][jcol][0] = rbl0;
    *(short8*)&Bl[cur][gate][kc+1][jcol][0] = rbl1;
    if (k0+32 < K2){
      int k = k0+32+ak;
      const float* src = (k<512)? (ah1+k) : (ah2+(k-512));
      a0 = *(const float4*)src; a1 = *(const float4*)(src+4);
      rbh0 = *(const short8*)(pBh + k0+32);  rbh1 = *(const short8*)(pBh + k0+40);
      rbl0 = *(const short8*)(pBl + k0+32);  rbl1 = *(const short8*)(pBl + k0+40);
    }
    __syncthreads();
    short8 afh = *(const short8*)&Ah[cur][w][lane>>4][lane&15][0];
    short8 afl = *(const short8*)&Al[cur][w][lane>>4][lane&15][0];
    #pragma unroll
    for (int g=0; g<4; ++g){
      short8 bh = *(const short8*)&Bh[cur][g][lane>>4][lane&15][0];
      short8 bl = *(const short8*)&Bl[cur][g][lane>>4][lane&15][0];
      acc[g] = __builtin_amdgcn_mfma_f32_16x16x32_bf16(afh, bh, acc[g], 0,0,0);
      acc[g] = __builtin_amdgcn_mfma_f32_16x16x32_bf16(afl, bh, acc[g], 0,0,0);
      acc[g] = __builtin_amdgcn_mfma_f32_16x16x32_bf16(afh, bl, acc[g], 0,0,0);
    }
    cur ^= 1;
  }
  int col = lane&15, jh = jh0+col;
  float bi  = b_ih[jh]      + b_hh[jh];
  float bff = b_ih[DK+jh]   + b_hh[DK+jh];
  float bg  = b_ih[2*DK+jh] + b_hh[2*DK+jh];
  float bo  = b_ih[3*DK+jh] + b_hh[3*DK+jh];
  #pragma unroll
  for (int r=0;r<4;++r){
    int n = n0 + w*16 + (lane>>4)*4 + r;
    size_t idx = (size_t)n*DK + jh;
    float iv = sigm(acc[0][r]+bi);
    float fv = sigm(acc[1][r]+bff);
    float gv = tanhf(acc[2][r]+bg);
    float ov = sigm(acc[3][r]+bo);
    float cn = fv*c2[idx] + iv*gv;
    c2[idx] = cn;
    h2_new[idx] = ov*tanhf(cn);
  }
}

// ---------------- attention + softmax + ctx + output projection; one block per n ----------------
// 512 threads; barrier-free QK and PV loops (direct global reads, wave-strided).
__global__ __launch_bounds__(512) void attn_k(
  const float* __restrict__ keys, const float* __restrict__ vals,
  const int* __restrict__ lens,
  const float* __restrict__ h2b, int par,
  float* __restrict__ ctx,
  const float* __restrict__ Wout, const float* __restrict__ b_out,
  float* __restrict__ out, int t)
{
  __shared__ float h2s[DK];
  __shared__ float e_s[TE];
  __shared__ float ctx_s[DV];
  __shared__ float ctxp[8][DV];
  __shared__ float red_s[16];
  int n = blockIdx.x, tid = threadIdx.x;
  int wv = tid>>6, lane = tid&63;
  const float* h2cur = h2b + (size_t)(par^1)*NB*DK;
  int L = lens[n] >> 3;           // lens // 8; only t < L are unmasked
  if (tid < DK) h2s[tid] = h2cur[n*DK + tid];
  __syncthreads();
  // q slice (32 floats at offset (lane&7)*32) into registers
  float qreg[32];
  {
    int off = (lane&7)*32;
    #pragma unroll
    for (int q=0;q<32;q+=4){
      float4 v4 = *(const float4*)&h2s[off+q];
      qreg[q]=v4.x; qreg[q+1]=v4.y; qreg[q+2]=v4.z; qreg[q+3]=v4.w;
    }
  }
  // QK: 8 lanes per row; rows strided by 64 across 8 waves; no barriers
  const float* kb = keys + (size_t)n*TE*DK;
  for (int r = wv*8 + (lane>>3); r < L; r += 64){
    const float* kr = kb + (size_t)r*DK + (lane&7)*32;
    float s = 0.f;
    #pragma unroll
    for (int q=0;q<32;q+=4){
      float4 kv = *(const float4*)(kr + q);
      s += kv.x*qreg[q] + kv.y*qreg[q+1] + kv.z*qreg[q+2] + kv.w*qreg[q+3];
    }
    s += __shfl_xor(s,1); s += __shfl_xor(s,2); s += __shfl_xor(s,4);
    if ((lane&7)==0) e_s[r] = s;
  }
  __syncthreads();
  // softmax over 512 slots
  float v = (tid < L) ? e_s[tid] : -1e30f;
  float m = v;
  #pragma unroll
  for (int o=1;o<64;o<<=1) m = fmaxf(m, __shfl_xor(m,o));
  if (lane==0) red_s[wv] = m;
  __syncthreads();
  m = red_s[0];
  #pragma unroll
  for (int q=1;q<8;++q) m = fmaxf(m, red_s[q]);
  float p = (tid < L) ? expf(v-m) : 0.f;
  float sm = p;
  #pragma unroll
  for (int o=1;o<64;o<<=1) sm += __shfl_xor(sm,o);
  if (lane==0) red_s[8+wv] = sm;
  __syncthreads();
  sm = red_s[8];
  #pragma unroll
  for (int q=1;q<8;++q) sm += red_s[8+q];
  e_s[tid] = p * (1.f/sm);      // own-slot write; no cross-thread hazard
  __syncthreads();
  // PV: wave-strided t; lane owns 4 v-dims; 1KB contiguous per wave-load
  float4 cacc = {0.f,0.f,0.f,0.f};
  const float* vb = vals + (size_t)n*TE*DV + lane*4;
  for (int r = wv; r < L; r += 8){
    float a = e_s[r];
    float4 vv4 = *(const float4*)(vb + (size_t)r*DV);
    cacc.x += a*vv4.x; cacc.y += a*vv4.y; cacc.z += a*vv4.z; cacc.w += a*vv4.w;
  }
  *(float4*)&ctxp[wv][lane*4] = cacc;
  __syncthreads();
  if (tid < DV){
    float cv = 0.f;
    #pragma unroll
    for (int q=0;q<8;++q) cv += ctxp[q][tid];
    ctx_s[tid] = cv;
    ctx[(size_t)n*DV + tid] = cv;
  }
  __syncthreads();
  // pred[v] = [h2 | ctx] . W_out[v] + b_out[v]  (16 lanes per vocab row)
  #pragma unroll
  for (int vb2=0; vb2<2; ++vb2){
    int vvv = vb2*32 + (tid>>4);
    if (vvv < NV){
      int kbase = (tid&15)*32;
      float s = 0.f;
      #pragma unroll
      for (int q=0;q<32;q+=4){
        float4 w4 = *(const float4*)(Wout + (size_t)vvv*512 + kbase + q);
        int k = kbase + q;
        const float* xs = (k < DK)? &h2s[k] : &ctx_s[k-DK];
        s += w4.x*xs[0] + w4.y*xs[1] + w4.z*xs[2] + w4.w*xs[3];
      }
      s += __shfl_xor(s,1); s += __shfl_xor(s,2); s += __shfl_xor(s,4); s += __shfl_xor(s,8);
      if ((tid&15)==0) out[((size_t)n*STEPS + t)*NV + vvv] = s + b_out[vvv];
    }
  }
}

// ---------------- host ----------------
extern "C" void kernel_launch(void* const* d_in, const int* in_sizes, int n_in,
                              void* d_out, int out_size, void* d_ws, size_t ws_size,
                              hipStream_t stream)
{
  const float* enc_key = (const float*)d_in[0];
  const float* enc_val = (const float*)d_in[1];
  const int*   text    = (const int*)d_in[2];
  const int*   lens    = (const int*)d_in[3];
  const float* emb     = (const float*)d_in[5];
  const float* W_ih1   = (const float*)d_in[6];
  const float* W_hh1   = (const float*)d_in[7];
  const float* b_ih1   = (const float*)d_in[8];
  const float* b_hh1   = (const float*)d_in[9];
  const float* W_ih2   = (const float*)d_in[10];
  const float* W_hh2   = (const float*)d_in[11];
  const float* b_ih2   = (const float*)d_in[12];
  const float* b_hh2   = (const float*)d_in[13];
  const float* W_out   = (const float*)d_in[14];
  const float* b_out   = (const float*)d_in[15];
  float* out = (float*)d_out;

  char* ws = (char*)d_ws;
  size_t off = 0;
  auto alloc = [&](size_t bytes)->char*{
    char* p = ws + off; off = (off + bytes + 255) & ~(size_t)255; return p;
  };

  u16* Wc1h = (u16*)alloc((size_t)2048*K1*2);     // 5.24 MB
  u16* Wc1l = (u16*)alloc((size_t)2048*K1*2);
  u16* Wc2h = (u16*)alloc((size_t)1024*K2*2);     // 1.57 MB
  u16* Wc2l = (u16*)alloc((size_t)1024*K2*2);
  float* h1b = (float*)alloc((size_t)2*NB*HH*4);
  float* h2b = (float*)alloc((size_t)2*NB*DK*4);
  float* ctx = (float*)alloc((size_t)NB*DV*4);
  float* c1  = (float*)alloc((size_t)NB*HH*4);
  float* c2  = (float*)alloc((size_t)NB*DK*4);

  // zero recurrent state (contiguous block h1b..c2)
  size_t zbytes = (char*)c2 + (size_t)NB*DK*4 - (char*)h1b;
  (void)hipMemsetAsync(h1b, 0, zbytes, stream);

  // one-time weight conversions (hi/lo split, concatenated [W_ih | W_hh])
  {
    int t8 = 2048*K1/8;
    conv_cat_split<<<(t8+255)/256, 256, 0, stream>>>(Wc1h, Wc1l, W_ih1, W_hh1, 768, 512, t8);
  }
  {
    int t8 = 1024*K2/8;
    conv_cat_split<<<(t8+255)/256, 256, 0, stream>>>(Wc2h, Wc2l, W_ih2, W_hh2, 512, 256, t8);
  }

  for (int t=0; t<STEPS; ++t){
    int par = t&1;
    lstm1_k<<<256, 128, 0, stream>>>(text, t, par, emb, ctx, h1b, c1, Wc1h, Wc1l, b_ih1, b_hh1);
    lstm2_k<<<128, 128, 0, stream>>>(par, h1b, h2b, c2, Wc2h, Wc2l, b_ih2, b_hh2);
    attn_k<<<256, 512, 0, stream>>>(enc_key, enc_val, lens, h2b, par, ctx, W_out, b_out, out, t);
  }
}